// Round 1
// baseline (767.013 us; speedup 1.0000x reference)
//
#include <hip/hip_runtime.h>

// gen_En: En[r,c] = sum_{i,j,m} w[i*32+j,m] * Ey[(i*32+j)*4+m, r-32i, c-32j]
// with w = (neff*N0/(neff+N0)) * U, valid when 0 <= r-32i < 192, 0 <= c-32j < 192.
// For an aligned 32x32 output tile (ti,tj), the contributing (i,j) sets are
// constant: i in [max(0,ti-5), min(31,ti)], same for j. Each Ey element is read
// exactly once across the whole grid -> pure streaming, no atomics, no init.

#define NB 32           // N blocks per dim
#define MODES 4
#define OUT_RES 32
#define EYS 192         // EY_SIZE
#define TOTAL 1184
#define N0F 1.5f
#define PLANE (EYS * EYS)   // 36864

__global__ __launch_bounds__(256) void en_gather_kernel(
    const float* __restrict__ U,
    const float* __restrict__ neff,
    const float* __restrict__ Ey,
    float* __restrict__ En)
{
    const int tj = blockIdx.x;   // output column tile index, 0..36
    const int ti = blockIdx.y;   // output row tile index, 0..36
    const int t  = threadIdx.x;

    const int i_lo = max(0, ti - 5);
    const int i_hi = min(NB - 1, ti);
    const int j_lo = max(0, tj - 5);
    const int j_hi = min(NB - 1, tj);
    const int ni = i_hi - i_lo + 1;   // <= 6
    const int nj = j_hi - j_lo + 1;   // <= 6
    const int nw = ni * nj * MODES;   // <= 144

    // Stage weights w[(pi*nj+pj)*4+m] in LDS
    __shared__ float wsh[6 * 6 * MODES];
    for (int idx = t; idx < nw; idx += 256) {
        const int m  = idx & 3;
        const int p  = idx >> 2;
        const int pj = p % nj;
        const int pi = p / nj;
        const int k  = (i_lo + pi) * NB + (j_lo + pj);
        const float e = neff[k * MODES + m];
        wsh[idx] = e * N0F / (e + N0F) * U[k * MODES + m];
    }
    __syncthreads();

    // Thread -> (row, 4 cols) within the 32x32 tile
    const int r_local = t >> 3;          // 0..31
    const int c_local = (t & 7) << 2;    // 0,4,...,28
    const int r0 = ti * OUT_RES;
    const int c0 = tj * OUT_RES;

    float4 acc = make_float4(0.f, 0.f, 0.f, 0.f);

    for (int pi = 0; pi < ni; ++pi) {
        const int i = i_lo + pi;
        const int x = r0 + r_local - i * OUT_RES;   // 0..191
        for (int pj = 0; pj < nj; ++pj) {
            const int j = j_lo + pj;
            const int y = c0 + c_local - j * OUT_RES;  // 0..188, mult of 4
            const int k = i * NB + j;
            const float* base = Ey + (size_t)(k * MODES) * PLANE
                                   + (size_t)x * EYS + y;
            const float* wp = &wsh[(pi * nj + pj) * MODES];
#pragma unroll
            for (int m = 0; m < MODES; ++m) {
                const float4 v =
                    *reinterpret_cast<const float4*>(base + (size_t)m * PLANE);
                const float w = wp[m];
                acc.x += w * v.x;
                acc.y += w * v.y;
                acc.z += w * v.z;
                acc.w += w * v.w;
            }
        }
    }

    float4* outp = reinterpret_cast<float4*>(
        En + (size_t)(r0 + r_local) * TOTAL + (c0 + c_local));
    *outp = acc;
}

extern "C" void kernel_launch(void* const* d_in, const int* in_sizes, int n_in,
                              void* d_out, int out_size, void* d_ws, size_t ws_size,
                              hipStream_t stream) {
    // inputs: hs (unused), U, neff, Ey — all fp32
    const float* U    = (const float*)d_in[1];
    const float* neff = (const float*)d_in[2];
    const float* Ey   = (const float*)d_in[3];
    float* En = (float*)d_out;

    dim3 grid(TOTAL / OUT_RES, TOTAL / OUT_RES);  // 37 x 37
    en_gather_kernel<<<grid, 256, 0, stream>>>(U, neff, Ey, En);
}